// Round 5
// baseline (274.049 us; speedup 1.0000x reference)
//
#include <hip/hip_runtime.h>
#include <hip/hip_bf16.h>

#define NNODES 50000
#define NEDGES 800000
#define NFEAT 128
#define NHID 128
#define NCLASS 10
#define NGRAPHS 256

#define NB 391   // (NNODES+127)/128 buckets of 128 nodes
#define HB 128   // histogram/scatter blocks

typedef __attribute__((ext_vector_type(8))) short short8;
typedef __attribute__((ext_vector_type(4))) short short4v;
typedef __attribute__((ext_vector_type(4))) float floatx4;

__device__ __forceinline__ float bf2f(unsigned short u) {
    union { unsigned i; float f; } c; c.i = ((unsigned)u) << 16; return c.f;
}
__device__ __forceinline__ unsigned short f2bf(float f) {
    union { float f; unsigned i; } c; c.f = f;
    unsigned x = c.i;
    unsigned r = (x + 0x7fffu + ((x >> 16) & 1u)) >> 16;
    return (unsigned short)r;
}
__device__ __forceinline__ float blo(unsigned v) { return bf2f((unsigned short)(v & 0xffffu)); }
__device__ __forceinline__ float bhi(unsigned v) { return bf2f((unsigned short)(v >> 16)); }

// ---------------- atomic-free CSR build: two-level counting sort ----------------
// hist layout TRANSPOSED: hist[bucket * HB + histblock] so bucket rows are contiguous.
__global__ __launch_bounds__(256) void k_hist(const int* __restrict__ dst,
                                              int* __restrict__ hist) {
    __shared__ int lh[NB];
    int tid = threadIdx.x;
    for (int b = tid; b < NB; b += 256) lh[b] = 0;
    __syncthreads();
    for (int i = blockIdx.x * 256 + tid; i < NEDGES; i += HB * 256)
        atomicAdd(&lh[dst[i] >> 7], 1);
    __syncthreads();
    for (int b = tid; b < NB; b += 256) hist[b * HB + blockIdx.x] = lh[b];
}

// Pass 2 (parallel): per-bucket wave scans over the 128 hist blocks -> base (local
// exclusive prefix), bucket totals -> boff (exclusive scan by one wave).
// Also graph start offsets via binary search on sorted batch.
__global__ __launch_bounds__(512) void k_scan2(const int* __restrict__ hist,
                                               int* __restrict__ base,
                                               int* __restrict__ boff,
                                               int* __restrict__ row_ptr,
                                               const int* __restrict__ batch,
                                               int* __restrict__ gstart) {
    __shared__ int tot[NB];
    int tid = threadIdx.x;
    int wid = tid >> 6, l = tid & 63;
    if (tid <= NGRAPHS) {
        int lo = 0, hi = NNODES;
        while (lo < hi) { int mid = (lo + hi) >> 1; if (batch[mid] < tid) lo = mid + 1; else hi = mid; }
        gstart[tid] = lo;
    }
    // phase A: per-bucket scan of 128 per-block counts (2 per lane)
    for (int q = wid; q < NB; q += 8) {
        int h0 = hist[q * HB + l];
        int h1 = hist[q * HB + 64 + l];
        int s0 = h0, s1 = h1;
        #pragma unroll
        for (int d = 1; d < 64; d <<= 1) {
            int y0 = __shfl_up(s0, d);
            int y1 = __shfl_up(s1, d);
            if (l >= d) { s0 += y0; s1 += y1; }
        }
        int t0 = __shfl(s0, 63);
        base[q * HB + l] = s0 - h0;
        base[q * HB + 64 + l] = s1 - h1 + t0;
        if (l == 63) tot[q] = t0 + s1;
    }
    __syncthreads();
    // phase B: exclusive scan of the NB bucket totals (single wave, 7 chunks)
    if (wid == 0) {
        int carry = 0;
        #pragma unroll
        for (int c = 0; c < (NB + 63) / 64; ++c) {
            int i = c * 64 + l;
            int v = (i < NB) ? tot[i] : 0;
            int s = v;
            #pragma unroll
            for (int d = 1; d < 64; d <<= 1) { int y = __shfl_up(s, d); if (l >= d) s += y; }
            if (i < NB) boff[i] = carry + s - v;
            carry += __shfl(s, 63);
        }
        if (l == 0) { boff[NB] = carry; row_ptr[NNODES] = carry; }
    }
}

// Pass 3: scatter edges into bucket-sorted ebuf; LDS cursors = boff + local base.
__global__ __launch_bounds__(256) void k_scatter(const int* __restrict__ src,
                                                 const int* __restrict__ dst,
                                                 const int* __restrict__ base,
                                                 const int* __restrict__ boff,
                                                 unsigned* __restrict__ ebuf) {
    __shared__ int cur[NB];
    int tid = threadIdx.x;
    for (int b = tid; b < NB; b += 256) cur[b] = boff[b] + base[b * HB + blockIdx.x];
    __syncthreads();
    for (int i = blockIdx.x * 256 + tid; i < NEDGES; i += HB * 256) {
        int d = dst[i];
        int bin = d >> 7;
        int pos = atomicAdd(&cur[bin], 1);                    // LDS atomic
        ebuf[pos] = (unsigned)src[i] | ((unsigned)(d & 127) << 16);
    }
}

// Pass 4: per-bucket local CSR (128 nodes) fully in LDS.
__global__ __launch_bounds__(256) void k_bcsr(const unsigned* __restrict__ ebuf,
                                              const int* __restrict__ boff,
                                              int* __restrict__ row_ptr,
                                              int* __restrict__ esrc) {
    __shared__ int deg[128];
    __shared__ int curs[128];
    int tid = threadIdx.x;
    int b = blockIdx.x;
    int s = boff[b], e = boff[b + 1];
    if (tid < 128) deg[tid] = 0;
    __syncthreads();
    for (int i = s + tid; i < e; i += 256) atomicAdd(&deg[ebuf[i] >> 16], 1);
    __syncthreads();
    if (tid == 0) {
        int run = s;
        for (int i = 0; i < 128; ++i) { curs[i] = run; run += deg[i]; }
    }
    __syncthreads();
    if (tid < 128) {
        int node = b * 128 + tid;
        if (node < NNODES) row_ptr[node] = curs[tid];
    }
    __syncthreads();
    for (int i = s + tid; i < e; i += 256) {
        unsigned pk = ebuf[i];
        int pos = atomicAdd(&curs[pk >> 16], 1);              // LDS atomic
        esrc[pos] = (int)(pk & 0xffffu);
    }
}

// ---------------- bf16 conversion (vectorized x4) of x and all 6 W matrices ------
__global__ void k_cvt(const float* __restrict__ x,
                      const float* __restrict__ w0, const float* __restrict__ w1,
                      const float* __restrict__ w2, const float* __restrict__ w3,
                      const float* __restrict__ w4, const float* __restrict__ w5,
                      unsigned short* __restrict__ xb, unsigned short* __restrict__ wb) {
    int gid = blockIdx.x * blockDim.x + threadIdx.x;   // group of 4 elements
    const int NX4 = NNODES * NFEAT / 4;
    const floatx4* srcv;
    short4v* dstv;
    if (gid < NX4) {
        srcv = (const floatx4*)x + gid;
        dstv = (short4v*)xb + gid;
    } else {
        int j = gid - NX4;
        if (j >= 6 * 4096) return;
        int m = j >> 12;
        int o4 = j & 4095;
        const float* w = (m == 0) ? w0 : (m == 1) ? w1 : (m == 2) ? w2
                       : (m == 3) ? w3 : (m == 4) ? w4 : w5;
        srcv = (const floatx4*)w + o4;
        dstv = (short4v*)wb + (m * 4096 + o4);
    }
    floatx4 v = *srcv;
    short4v o;
    #pragma unroll
    for (int k = 0; k < 4; ++k) o[k] = (short)f2bf(v[k]);
    *dstv = o;
}

// ---------------- scatter-mean as CSR gather: wave per node, 8 gathers in flight --
__global__ __launch_bounds__(256) void k_agg(const unsigned short* __restrict__ feat,
                                             const int* __restrict__ row_ptr,
                                             const int* __restrict__ esrc,
                                             unsigned short* __restrict__ agg) {
    int w = threadIdx.x >> 6;
    int l = threadIdx.x & 63;
    int n = blockIdx.x * 4 + w;
    if (n >= NNODES) return;
    int beg = row_ptr[n], end = row_ptr[n + 1];
    int nb = end - beg;
    const unsigned* feat32 = (const unsigned*)feat;  // 2 bf16 per dword, row stride 64
    float a0 = 0.f, a1 = 0.f;
    for (int base = 0; base < nb; base += 64) {
        int rem = nb - base;
        int cnt = rem < 64 ? rem : 64;
        int myidx = (l < cnt) ? esrc[beg + base + l] : 0;   // coalesced index load
        int j = 0;
        for (; j + 8 <= cnt; j += 8) {
            int s0 = __shfl(myidx, j);
            int s1 = __shfl(myidx, j + 1);
            int s2 = __shfl(myidx, j + 2);
            int s3 = __shfl(myidx, j + 3);
            int s4 = __shfl(myidx, j + 4);
            int s5 = __shfl(myidx, j + 5);
            int s6 = __shfl(myidx, j + 6);
            int s7 = __shfl(myidx, j + 7);
            unsigned v0 = feat32[s0 * 64 + l];
            unsigned v1 = feat32[s1 * 64 + l];
            unsigned v2 = feat32[s2 * 64 + l];
            unsigned v3 = feat32[s3 * 64 + l];
            unsigned v4 = feat32[s4 * 64 + l];
            unsigned v5 = feat32[s5 * 64 + l];
            unsigned v6 = feat32[s6 * 64 + l];
            unsigned v7 = feat32[s7 * 64 + l];
            a0 += ((blo(v0) + blo(v1)) + (blo(v2) + blo(v3)))
                + ((blo(v4) + blo(v5)) + (blo(v6) + blo(v7)));
            a1 += ((bhi(v0) + bhi(v1)) + (bhi(v2) + bhi(v3)))
                + ((bhi(v4) + bhi(v5)) + (bhi(v6) + bhi(v7)));
        }
        for (; j + 4 <= cnt; j += 4) {
            int s0 = __shfl(myidx, j);
            int s1 = __shfl(myidx, j + 1);
            int s2 = __shfl(myidx, j + 2);
            int s3 = __shfl(myidx, j + 3);
            unsigned v0 = feat32[s0 * 64 + l];
            unsigned v1 = feat32[s1 * 64 + l];
            unsigned v2 = feat32[s2 * 64 + l];
            unsigned v3 = feat32[s3 * 64 + l];
            a0 += (blo(v0) + blo(v1)) + (blo(v2) + blo(v3));
            a1 += (bhi(v0) + bhi(v1)) + (bhi(v2) + bhi(v3));
        }
        for (; j < cnt; ++j) {
            int s0 = __shfl(myidx, j);
            unsigned v0 = feat32[s0 * 64 + l];
            a0 += blo(v0);
            a1 += bhi(v0);
        }
    }
    float inv = 1.0f / (float)max(nb, 1);
    unsigned o = ((unsigned)f2bf(a0 * inv)) | (((unsigned)f2bf(a1 * inv)) << 16);
    ((unsigned*)agg)[n * 64 + l] = o;
}

// ---------------- fused dual-matvec GEMM: C = [agg|feat] @ [Wn|Ws]^T, +bias, relu ----
// 8 waves/block, wave w owns output stripe nt=w. B fragments loaded ONCE.
// unroll 2 on row-tiles: 2-deep load pipeline without VGPR blowup (keeps >=2 blocks/CU).
__global__ __launch_bounds__(512) void k_gemm(const unsigned short* __restrict__ A1,
                                              const unsigned short* __restrict__ A2,
                                              const unsigned short* __restrict__ Bn,
                                              const unsigned short* __restrict__ Bs,
                                              const float* __restrict__ bias,
                                              unsigned short* __restrict__ out) {
    int wid = threadIdx.x >> 6;   // 0..7 = nt stripe
    int l = threadIdx.x & 63;
    int r = l & 15;               // row-in-tile for A, col-in-tile for B/C
    int gk = l >> 4;              // k-group (8 elements each)
    int m0 = blockIdx.x * 128;

    short8 bf[8];
    #pragma unroll
    for (int kt = 0; kt < 8; ++kt) {
        const unsigned short* Bbase = (kt < 4 ? Bn : Bs);
        int kk = (kt & 3) * 32 + gk * 8;
        bf[kt] = *(const short8*)(Bbase + (wid * 16 + r) * 128 + kk);
    }
    int o = wid * 16 + r;
    float bias_v = bias[o];

    #pragma unroll 2
    for (int rt = 0; rt < 8; ++rt) {
        int row = m0 + rt * 16 + r;
        int lrow = row < NNODES ? row : NNODES - 1;   // clamp loads; stores guarded
        short8 af[8];
        #pragma unroll
        for (int kt = 0; kt < 8; ++kt) {
            const unsigned short* Ap = (kt < 4 ? A1 : A2) + lrow * 128 + (kt & 3) * 32 + gk * 8;
            af[kt] = *(const short8*)Ap;
        }
        floatx4 acc = {0.f, 0.f, 0.f, 0.f};
        #pragma unroll
        for (int kt = 0; kt < 8; ++kt)
            acc = __builtin_amdgcn_mfma_f32_16x16x32_bf16(af[kt], bf[kt], acc, 0, 0, 0);
        // C/D layout: col = lane&15 (=r), row-in-tile = gk*4 + j
        #pragma unroll
        for (int j = 0; j < 4; ++j) {
            int mrow = m0 + rt * 16 + gk * 4 + j;
            if (mrow < NNODES) {
                float v = acc[j] + bias_v;
                v = v > 0.f ? v : 0.f;
                out[mrow * 128 + o] = f2bf(v);
            }
        }
    }
}

// ---------------- mean pool: 8 partial-sum blocks per graph ----------------
__global__ __launch_bounds__(256) void k_pool(const unsigned short* __restrict__ h,
                                              const int* __restrict__ gstart,
                                              float* __restrict__ part) {
    int g = blockIdx.x >> 3;
    int c = blockIdx.x & 7;
    int s = gstart[g], e = gstart[g + 1];
    int len = e - s;
    int cs = s + (len * c) / 8;
    int ce = s + (len * (c + 1)) / 8;
    int w = threadIdx.x >> 6;
    int l = threadIdx.x & 63;
    const unsigned* h32 = (const unsigned*)h;
    float a0 = 0.f, a1 = 0.f;
    for (int n = cs + w; n < ce; n += 4) {
        unsigned v = h32[n * 64 + l];
        a0 += blo(v);
        a1 += bhi(v);
    }
    __shared__ float red[4][128];
    red[w][2 * l] = a0;
    red[w][2 * l + 1] = a1;
    __syncthreads();
    if (w == 0) {
        float r0 = (red[0][2 * l] + red[1][2 * l]) + (red[2][2 * l] + red[3][2 * l]);
        float r1 = (red[0][2 * l + 1] + red[1][2 * l + 1]) + (red[2][2 * l + 1] + red[3][2 * l + 1]);
        float* dst = part + (size_t)(g * 8 + c) * 128;
        dst[2 * l] = r0;
        dst[2 * l + 1] = r1;
    }
}

// ---------------- head: reduce partials, logits + log_softmax (f32) ----------------
__global__ __launch_bounds__(128) void k_head(const float* __restrict__ part,
                                              const int* __restrict__ gstart,
                                              const float* __restrict__ Wlin,
                                              const float* __restrict__ blin,
                                              float* __restrict__ out) {
    int gi = blockIdx.x;
    __shared__ float gl[128];
    __shared__ float lg[NCLASS];
    int t = threadIdx.x;
    float s = 0.f;
    #pragma unroll
    for (int c = 0; c < 8; ++c) s += part[(size_t)(gi * 8 + c) * 128 + t];
    int len = gstart[gi + 1] - gstart[gi];
    gl[t] = s / (float)max(len, 1);
    __syncthreads();
    if (t < NCLASS) {
        float a = blin[t];
        #pragma unroll 16
        for (int i = 0; i < 128; ++i) a += gl[i] * Wlin[t * 128 + i];
        lg[t] = a;
    }
    __syncthreads();
    if (t == 0) {
        float m = lg[0];
        for (int k = 1; k < NCLASS; ++k) m = fmaxf(m, lg[k]);
        float sum = 0.f;
        for (int k = 0; k < NCLASS; ++k) sum += expf(lg[k] - m);
        float ls = logf(sum) + m;
        for (int k = 0; k < NCLASS; ++k) out[gi * NCLASS + k] = lg[k] - ls;
    }
}

extern "C" void kernel_launch(void* const* d_in, const int* in_sizes, int n_in,
                              void* d_out, int out_size, void* d_ws, size_t ws_size,
                              hipStream_t stream) {
    const float* x    = (const float*)d_in[0];
    const int*   ei   = (const int*)d_in[1];
    const int*   src  = ei;
    const int*   dst  = ei + NEDGES;
    const int*   batch= (const int*)d_in[2];
    const float* W1n  = (const float*)d_in[3];
    const float* b1   = (const float*)d_in[4];
    const float* W1s  = (const float*)d_in[5];
    const float* W2n  = (const float*)d_in[6];
    const float* b2   = (const float*)d_in[7];
    const float* W2s  = (const float*)d_in[8];
    const float* W3n  = (const float*)d_in[9];
    const float* b3   = (const float*)d_in[10];
    const float* W3s  = (const float*)d_in[11];
    const float* Wlin = (const float*)d_in[12];
    const float* blin = (const float*)d_in[13];
    float* out = (float*)d_out;

    char* p = (char*)d_ws;
    auto alloc = [&](size_t bytes) -> void* {
        void* r = (void*)p;
        p += (bytes + 255) & ~(size_t)255;
        return r;
    };
    unsigned short* xb   = (unsigned short*)alloc((size_t)NNODES * NFEAT * 2);
    unsigned short* hA   = (unsigned short*)alloc((size_t)NNODES * NHID * 2);
    unsigned short* hB   = (unsigned short*)alloc((size_t)NNODES * NHID * 2);
    unsigned short* agg  = (unsigned short*)alloc((size_t)NNODES * NHID * 2);
    unsigned short* wb   = (unsigned short*)alloc((size_t)6 * 16384 * 2);
    int* hist    = (int*)alloc((size_t)NB * HB * 4);
    int* base    = (int*)alloc((size_t)NB * HB * 4);
    int* boff    = (int*)alloc((size_t)(NB + 1) * 4);
    int* row_ptr = (int*)alloc((size_t)(NNODES + 1) * 4);
    int* gstart  = (int*)alloc((size_t)(NGRAPHS + 1) * 4);
    unsigned* ebuf = (unsigned*)alloc((size_t)NEDGES * 4);
    int* esrc    = (int*)alloc((size_t)NEDGES * 4);
    float* part  = (float*)alloc((size_t)NGRAPHS * 8 * NHID * 4);

    // CSR build (atomic-free counting sort) + graph ranges
    k_hist<<<HB, 256, 0, stream>>>(dst, hist);
    k_scan2<<<1, 512, 0, stream>>>(hist, base, boff, row_ptr, batch, gstart);
    k_scatter<<<HB, 256, 0, stream>>>(src, dst, base, boff, ebuf);
    k_bcsr<<<NB, 256, 0, stream>>>(ebuf, boff, row_ptr, esrc);

    // convert x + weights to bf16 (4 elems/thread)
    {
        int total4 = NNODES * NFEAT / 4 + 6 * 4096;
        k_cvt<<<(total4 + 255) / 256, 256, 0, stream>>>(x, W1n, W1s, W2n, W2s, W3n, W3s, xb, wb);
    }

    const int aggGrid  = (NNODES + 3) / 4;
    const int gemmGrid = (NNODES + 127) / 128;

    // layer 1
    k_agg<<<aggGrid, 256, 0, stream>>>(xb, row_ptr, esrc, agg);
    k_gemm<<<gemmGrid, 512, 0, stream>>>(agg, xb, wb + 0 * 16384, wb + 1 * 16384, b1, hA);
    // layer 2
    k_agg<<<aggGrid, 256, 0, stream>>>(hA, row_ptr, esrc, agg);
    k_gemm<<<gemmGrid, 512, 0, stream>>>(agg, hA, wb + 2 * 16384, wb + 3 * 16384, b2, hB);
    // layer 3
    k_agg<<<aggGrid, 256, 0, stream>>>(hB, row_ptr, esrc, agg);
    k_gemm<<<gemmGrid, 512, 0, stream>>>(agg, hB, wb + 4 * 16384, wb + 5 * 16384, b3, hA);

    // pool + head
    k_pool<<<NGRAPHS * 8, 256, 0, stream>>>(hA, gstart, part);
    k_head<<<NGRAPHS, 128, 0, stream>>>(part, gstart, Wlin, blin, out);
}

// Round 6
// 218.614 us; speedup vs baseline: 1.2536x; 1.2536x over previous
//
#include <hip/hip_runtime.h>
#include <hip/hip_bf16.h>

#define NNODES 50000
#define NEDGES 800000
#define NFEAT 128
#define NHID 128
#define NCLASS 10
#define NGRAPHS 256

#define NB 391   // (NNODES+127)/128 buckets of 128 nodes
#define HB 128   // histogram/scatter blocks

typedef __attribute__((ext_vector_type(8))) short short8;
typedef __attribute__((ext_vector_type(4))) short short4v;
typedef __attribute__((ext_vector_type(4))) float floatx4;

__device__ __forceinline__ float bf2f(unsigned short u) {
    union { unsigned i; float f; } c; c.i = ((unsigned)u) << 16; return c.f;
}
__device__ __forceinline__ unsigned short f2bf(float f) {
    union { float f; unsigned i; } c; c.f = f;
    unsigned x = c.i;
    unsigned r = (x + 0x7fffu + ((x >> 16) & 1u)) >> 16;
    return (unsigned short)r;
}
__device__ __forceinline__ float blo(unsigned v) { return bf2f((unsigned short)(v & 0xffffu)); }
__device__ __forceinline__ float bhi(unsigned v) { return bf2f((unsigned short)(v >> 16)); }

__device__ __forceinline__ void gload_lds16(const void* gsrc, void* ldst) {
    __builtin_amdgcn_global_load_lds(
        (const __attribute__((address_space(1))) void*)gsrc,
        (__attribute__((address_space(3))) void*)ldst, 16, 0, 0);
}

// ---------------- atomic-free CSR build: two-level counting sort ----------------
// hist layout TRANSPOSED: hist[bucket * HB + histblock] so bucket rows are contiguous.
__global__ __launch_bounds__(256) void k_hist(const int* __restrict__ dst,
                                              int* __restrict__ hist) {
    __shared__ int lh[NB];
    int tid = threadIdx.x;
    for (int b = tid; b < NB; b += 256) lh[b] = 0;
    __syncthreads();
    for (int i = blockIdx.x * 256 + tid; i < NEDGES; i += HB * 256)
        atomicAdd(&lh[dst[i] >> 7], 1);
    __syncthreads();
    for (int b = tid; b < NB; b += 256) hist[b * HB + blockIdx.x] = lh[b];
}

// Pass 2 (parallel): per-bucket wave scans -> base, bucket totals -> boff.
// Also graph start offsets via binary search on sorted batch.
__global__ __launch_bounds__(512) void k_scan2(const int* __restrict__ hist,
                                               int* __restrict__ base,
                                               int* __restrict__ boff,
                                               int* __restrict__ row_ptr,
                                               const int* __restrict__ batch,
                                               int* __restrict__ gstart) {
    __shared__ int tot[NB];
    int tid = threadIdx.x;
    int wid = tid >> 6, l = tid & 63;
    if (tid <= NGRAPHS) {
        int lo = 0, hi = NNODES;
        while (lo < hi) { int mid = (lo + hi) >> 1; if (batch[mid] < tid) lo = mid + 1; else hi = mid; }
        gstart[tid] = lo;
    }
    for (int q = wid; q < NB; q += 8) {
        int h0 = hist[q * HB + l];
        int h1 = hist[q * HB + 64 + l];
        int s0 = h0, s1 = h1;
        #pragma unroll
        for (int d = 1; d < 64; d <<= 1) {
            int y0 = __shfl_up(s0, d);
            int y1 = __shfl_up(s1, d);
            if (l >= d) { s0 += y0; s1 += y1; }
        }
        int t0 = __shfl(s0, 63);
        base[q * HB + l] = s0 - h0;
        base[q * HB + 64 + l] = s1 - h1 + t0;
        if (l == 63) tot[q] = t0 + s1;
    }
    __syncthreads();
    if (wid == 0) {
        int carry = 0;
        #pragma unroll
        for (int c = 0; c < (NB + 63) / 64; ++c) {
            int i = c * 64 + l;
            int v = (i < NB) ? tot[i] : 0;
            int s = v;
            #pragma unroll
            for (int d = 1; d < 64; d <<= 1) { int y = __shfl_up(s, d); if (l >= d) s += y; }
            if (i < NB) boff[i] = carry + s - v;
            carry += __shfl(s, 63);
        }
        if (l == 0) { boff[NB] = carry; row_ptr[NNODES] = carry; }
    }
}

// Pass 3: scatter edges into bucket-sorted ebuf; LDS cursors = boff + local base.
__global__ __launch_bounds__(256) void k_scatter(const int* __restrict__ src,
                                                 const int* __restrict__ dst,
                                                 const int* __restrict__ base,
                                                 const int* __restrict__ boff,
                                                 unsigned* __restrict__ ebuf) {
    __shared__ int cur[NB];
    int tid = threadIdx.x;
    for (int b = tid; b < NB; b += 256) cur[b] = boff[b] + base[b * HB + blockIdx.x];
    __syncthreads();
    for (int i = blockIdx.x * 256 + tid; i < NEDGES; i += HB * 256) {
        int d = dst[i];
        int bin = d >> 7;
        int pos = atomicAdd(&cur[bin], 1);                    // LDS atomic
        ebuf[pos] = (unsigned)src[i] | ((unsigned)(d & 127) << 16);
    }
}

// Pass 4: per-bucket local CSR (128 nodes) fully in LDS.
__global__ __launch_bounds__(256) void k_bcsr(const unsigned* __restrict__ ebuf,
                                              const int* __restrict__ boff,
                                              int* __restrict__ row_ptr,
                                              int* __restrict__ esrc) {
    __shared__ int deg[128];
    __shared__ int curs[128];
    int tid = threadIdx.x;
    int b = blockIdx.x;
    int s = boff[b], e = boff[b + 1];
    if (tid < 128) deg[tid] = 0;
    __syncthreads();
    for (int i = s + tid; i < e; i += 256) atomicAdd(&deg[ebuf[i] >> 16], 1);
    __syncthreads();
    if (tid == 0) {
        int run = s;
        for (int i = 0; i < 128; ++i) { curs[i] = run; run += deg[i]; }
    }
    __syncthreads();
    if (tid < 128) {
        int node = b * 128 + tid;
        if (node < NNODES) row_ptr[node] = curs[tid];
    }
    __syncthreads();
    for (int i = s + tid; i < e; i += 256) {
        unsigned pk = ebuf[i];
        int pos = atomicAdd(&curs[pk >> 16], 1);              // LDS atomic
        esrc[pos] = (int)(pk & 0xffffu);
    }
}

// ---------------- bf16 conversion (vectorized x4) of x and all 6 W matrices ------
__global__ void k_cvt(const float* __restrict__ x,
                      const float* __restrict__ w0, const float* __restrict__ w1,
                      const float* __restrict__ w2, const float* __restrict__ w3,
                      const float* __restrict__ w4, const float* __restrict__ w5,
                      unsigned short* __restrict__ xb, unsigned short* __restrict__ wb) {
    int gid = blockIdx.x * blockDim.x + threadIdx.x;   // group of 4 elements
    const int NX4 = NNODES * NFEAT / 4;
    const floatx4* srcv;
    short4v* dstv;
    if (gid < NX4) {
        srcv = (const floatx4*)x + gid;
        dstv = (short4v*)xb + gid;
    } else {
        int j = gid - NX4;
        if (j >= 6 * 4096) return;
        int m = j >> 12;
        int o4 = j & 4095;
        const float* w = (m == 0) ? w0 : (m == 1) ? w1 : (m == 2) ? w2
                       : (m == 3) ? w3 : (m == 4) ? w4 : w5;
        srcv = (const floatx4*)w + o4;
        dstv = (short4v*)wb + (m * 4096 + o4);
    }
    floatx4 v = *srcv;
    short4v o;
    #pragma unroll
    for (int k = 0; k < 4; ++k) o[k] = (short)f2bf(v[k]);
    *dstv = o;
}

// ---------------- scatter-mean as CSR gather: wave per node, 4 gathers in flight --
__global__ __launch_bounds__(256) void k_agg(const unsigned short* __restrict__ feat,
                                             const int* __restrict__ row_ptr,
                                             const int* __restrict__ esrc,
                                             unsigned short* __restrict__ agg) {
    int w = threadIdx.x >> 6;
    int l = threadIdx.x & 63;
    int n = blockIdx.x * 4 + w;
    if (n >= NNODES) return;
    int beg = row_ptr[n], end = row_ptr[n + 1];
    int nb = end - beg;
    const unsigned* feat32 = (const unsigned*)feat;  // 2 bf16 per dword, row stride 64
    float a0 = 0.f, a1 = 0.f;
    for (int base = 0; base < nb; base += 64) {
        int rem = nb - base;
        int cnt = rem < 64 ? rem : 64;
        int myidx = (l < cnt) ? esrc[beg + base + l] : 0;   // coalesced index load
        int j = 0;
        for (; j + 4 <= cnt; j += 4) {
            int s0 = __shfl(myidx, j);
            int s1 = __shfl(myidx, j + 1);
            int s2 = __shfl(myidx, j + 2);
            int s3 = __shfl(myidx, j + 3);
            unsigned v0 = feat32[s0 * 64 + l];
            unsigned v1 = feat32[s1 * 64 + l];
            unsigned v2 = feat32[s2 * 64 + l];
            unsigned v3 = feat32[s3 * 64 + l];
            a0 += (blo(v0) + blo(v1)) + (blo(v2) + blo(v3));
            a1 += (bhi(v0) + bhi(v1)) + (bhi(v2) + bhi(v3));
        }
        for (; j < cnt; ++j) {
            int s0 = __shfl(myidx, j);
            unsigned v0 = feat32[s0 * 64 + l];
            a0 += blo(v0);
            a1 += bhi(v0);
        }
    }
    float inv = 1.0f / (float)max(nb, 1);
    unsigned o = ((unsigned)f2bf(a0 * inv)) | (((unsigned)f2bf(a1 * inv)) << 16);
    ((unsigned*)agg)[n * 64 + l] = o;
}

// ---------------- fused dual-matvec GEMM v3: LDS-staged A shared by 8 waves --------
// C = [agg|feat] @ [Wn|Ws]^T + bias, relu. Block = 64 rows (4 tiles of 16), 8 waves,
// wave w owns col stripe w*16..w*16+15. B fragments in regs (loaded once).
// A tile (16 rows x 256 K = 8KB) staged via global_load_lds (1 inst/thread),
// double-buffered, counted vmcnt(1); XOR-swizzle (C^=R&15 on 16B chunks) applied
// via pre-swizzled GLOBAL source + swizzled ds_read (both-sides rule).
__global__ __launch_bounds__(512, 4) void k_gemm(const unsigned short* __restrict__ A1,
                                                 const unsigned short* __restrict__ A2,
                                                 const unsigned short* __restrict__ Bn,
                                                 const unsigned short* __restrict__ Bs,
                                                 const float* __restrict__ bias,
                                                 unsigned short* __restrict__ out) {
    __shared__ __align__(16) unsigned short ldsA[2][4096];   // 2 x 8KB: [32 rows][128 elems]
    int w = threadIdx.x >> 6;     // wave = col stripe
    int l = threadIdx.x & 63;
    int r = l & 15;               // row-in-tile for A, col-in-tile for B/C
    int gk = l >> 4;              // k-group (8 elements each)
    int m0 = blockIdx.x * 64;

    short8 bf[8];
    #pragma unroll
    for (int kt = 0; kt < 8; ++kt) {
        const unsigned short* Bbase = (kt < 4 ? Bn : Bs);
        bf[kt] = *(const short8*)(Bbase + (w * 16 + r) * 128 + (kt & 3) * 32 + gk * 8);
    }
    int o = w * 16 + r;
    float bias_v = bias[o];

    // staging thread map: R = w*4 + (l>>4) in [0,32): R<16 -> A1 row, else A2 row.
    int R = (w << 2) + (l >> 4);
    int rin = R & 15;
    const unsigned short* Ab = (R < 16) ? A1 : A2;
    int gcol = ((l & 15) ^ rin) << 3;     // pre-swizzled source column (elements)

    auto stage = [&](int t) {
        int nrow = m0 + t * 16 + rin;
        if (nrow >= NNODES) nrow = NNODES - 1;
        gload_lds16(Ab + (size_t)nrow * 128 + gcol, &ldsA[t & 1][w * 512]);
    };

    stage(0);
    #pragma unroll
    for (int t = 0; t < 4; ++t) {
        if (t < 3) {
            stage(t + 1);
            asm volatile("s_waitcnt vmcnt(1)" ::: "memory");
        } else {
            asm volatile("s_waitcnt vmcnt(0)" ::: "memory");
        }
        __builtin_amdgcn_s_barrier();
        __builtin_amdgcn_sched_barrier(0);

        const unsigned short* Lb = &ldsA[t & 1][0];
        short8 af[8];
        #pragma unroll
        for (int kt = 0; kt < 8; ++kt) {
            int Rr = (kt < 4) ? r : (16 + r);
            int Cr = ((((kt & 3) << 2) + gk) ^ r) << 3;     // swizzled read col
            af[kt] = *(const short8*)(Lb + Rr * 128 + Cr);
        }
        floatx4 acc = {0.f, 0.f, 0.f, 0.f};
        #pragma unroll
        for (int kt = 0; kt < 8; ++kt)
            acc = __builtin_amdgcn_mfma_f32_16x16x32_bf16(af[kt], bf[kt], acc, 0, 0, 0);

        // C/D layout: col = lane&15 (=r), row-in-tile = gk*4 + j
        #pragma unroll
        for (int j = 0; j < 4; ++j) {
            int mrow = m0 + t * 16 + gk * 4 + j;
            if (mrow < NNODES) {
                float v = acc[j] + bias_v;
                v = v > 0.f ? v : 0.f;
                out[mrow * 128 + o] = f2bf(v);
            }
        }
        __builtin_amdgcn_s_barrier();       // all waves done reading buf before overwrite
        __builtin_amdgcn_sched_barrier(0);
    }
}

// ---------------- mean pool: 8 partial-sum blocks per graph ----------------
__global__ __launch_bounds__(256) void k_pool(const unsigned short* __restrict__ h,
                                              const int* __restrict__ gstart,
                                              float* __restrict__ part) {
    int g = blockIdx.x >> 3;
    int c = blockIdx.x & 7;
    int s = gstart[g], e = gstart[g + 1];
    int len = e - s;
    int cs = s + (len * c) / 8;
    int ce = s + (len * (c + 1)) / 8;
    int w = threadIdx.x >> 6;
    int l = threadIdx.x & 63;
    const unsigned* h32 = (const unsigned*)h;
    float a0 = 0.f, a1 = 0.f;
    for (int n = cs + w; n < ce; n += 4) {
        unsigned v = h32[n * 64 + l];
        a0 += blo(v);
        a1 += bhi(v);
    }
    __shared__ float red[4][128];
    red[w][2 * l] = a0;
    red[w][2 * l + 1] = a1;
    __syncthreads();
    if (w == 0) {
        float r0 = (red[0][2 * l] + red[1][2 * l]) + (red[2][2 * l] + red[3][2 * l]);
        float r1 = (red[0][2 * l + 1] + red[1][2 * l + 1]) + (red[2][2 * l + 1] + red[3][2 * l + 1]);
        float* dst = part + (size_t)(g * 8 + c) * 128;
        dst[2 * l] = r0;
        dst[2 * l + 1] = r1;
    }
}

// ---------------- head: reduce partials, logits + log_softmax (f32) ----------------
__global__ __launch_bounds__(128) void k_head(const float* __restrict__ part,
                                              const int* __restrict__ gstart,
                                              const float* __restrict__ Wlin,
                                              const float* __restrict__ blin,
                                              float* __restrict__ out) {
    int gi = blockIdx.x;
    __shared__ float gl[128];
    __shared__ float lg[NCLASS];
    int t = threadIdx.x;
    float s = 0.f;
    #pragma unroll
    for (int c = 0; c < 8; ++c) s += part[(size_t)(gi * 8 + c) * 128 + t];
    int len = gstart[gi + 1] - gstart[gi];
    gl[t] = s / (float)max(len, 1);
    __syncthreads();
    if (t < NCLASS) {
        float a = blin[t];
        #pragma unroll 16
        for (int i = 0; i < 128; ++i) a += gl[i] * Wlin[t * 128 + i];
        lg[t] = a;
    }
    __syncthreads();
    if (t == 0) {
        float m = lg[0];
        for (int k = 1; k < NCLASS; ++k) m = fmaxf(m, lg[k]);
        float sum = 0.f;
        for (int k = 0; k < NCLASS; ++k) sum += expf(lg[k] - m);
        float ls = logf(sum) + m;
        for (int k = 0; k < NCLASS; ++k) out[gi * NCLASS + k] = lg[k] - ls;
    }
}

extern "C" void kernel_launch(void* const* d_in, const int* in_sizes, int n_in,
                              void* d_out, int out_size, void* d_ws, size_t ws_size,
                              hipStream_t stream) {
    const float* x    = (const float*)d_in[0];
    const int*   ei   = (const int*)d_in[1];
    const int*   src  = ei;
    const int*   dst  = ei + NEDGES;
    const int*   batch= (const int*)d_in[2];
    const float* W1n  = (const float*)d_in[3];
    const float* b1   = (const float*)d_in[4];
    const float* W1s  = (const float*)d_in[5];
    const float* W2n  = (const float*)d_in[6];
    const float* b2   = (const float*)d_in[7];
    const float* W2s  = (const float*)d_in[8];
    const float* W3n  = (const float*)d_in[9];
    const float* b3   = (const float*)d_in[10];
    const float* W3s  = (const float*)d_in[11];
    const float* Wlin = (const float*)d_in[12];
    const float* blin = (const float*)d_in[13];
    float* out = (float*)d_out;

    char* p = (char*)d_ws;
    auto alloc = [&](size_t bytes) -> void* {
        void* r = (void*)p;
        p += (bytes + 255) & ~(size_t)255;
        return r;
    };
    unsigned short* xb   = (unsigned short*)alloc((size_t)NNODES * NFEAT * 2);
    unsigned short* hA   = (unsigned short*)alloc((size_t)NNODES * NHID * 2);
    unsigned short* hB   = (unsigned short*)alloc((size_t)NNODES * NHID * 2);
    unsigned short* agg  = (unsigned short*)alloc((size_t)NNODES * NHID * 2);
    unsigned short* wb   = (unsigned short*)alloc((size_t)6 * 16384 * 2);
    int* hist    = (int*)alloc((size_t)NB * HB * 4);
    int* base    = (int*)alloc((size_t)NB * HB * 4);
    int* boff    = (int*)alloc((size_t)(NB + 1) * 4);
    int* row_ptr = (int*)alloc((size_t)(NNODES + 1) * 4);
    int* gstart  = (int*)alloc((size_t)(NGRAPHS + 1) * 4);
    unsigned* ebuf = (unsigned*)alloc((size_t)NEDGES * 4);
    int* esrc    = (int*)alloc((size_t)NEDGES * 4);
    float* part  = (float*)alloc((size_t)NGRAPHS * 8 * NHID * 4);

    // CSR build (atomic-free counting sort) + graph ranges
    k_hist<<<HB, 256, 0, stream>>>(dst, hist);
    k_scan2<<<1, 512, 0, stream>>>(hist, base, boff, row_ptr, batch, gstart);
    k_scatter<<<HB, 256, 0, stream>>>(src, dst, base, boff, ebuf);
    k_bcsr<<<NB, 256, 0, stream>>>(ebuf, boff, row_ptr, esrc);

    // convert x + weights to bf16 (4 elems/thread)
    {
        int total4 = NNODES * NFEAT / 4 + 6 * 4096;
        k_cvt<<<(total4 + 255) / 256, 256, 0, stream>>>(x, W1n, W1s, W2n, W2s, W3n, W3s, xb, wb);
    }

    const int aggGrid  = (NNODES + 3) / 4;
    const int gemmGrid = (NNODES + 63) / 64;

    // layer 1
    k_agg<<<aggGrid, 256, 0, stream>>>(xb, row_ptr, esrc, agg);
    k_gemm<<<gemmGrid, 512, 0, stream>>>(agg, xb, wb + 0 * 16384, wb + 1 * 16384, b1, hA);
    // layer 2
    k_agg<<<aggGrid, 256, 0, stream>>>(hA, row_ptr, esrc, agg);
    k_gemm<<<gemmGrid, 512, 0, stream>>>(agg, hA, wb + 2 * 16384, wb + 3 * 16384, b2, hB);
    // layer 3
    k_agg<<<aggGrid, 256, 0, stream>>>(hB, row_ptr, esrc, agg);
    k_gemm<<<gemmGrid, 512, 0, stream>>>(agg, hB, wb + 4 * 16384, wb + 5 * 16384, b3, hA);

    // pool + head
    k_pool<<<NGRAPHS * 8, 256, 0, stream>>>(hA, gstart, part);
    k_head<<<NGRAPHS, 128, 0, stream>>>(part, gstart, Wlin, blin, out);
}

// Round 7
// 209.467 us; speedup vs baseline: 1.3083x; 1.0437x over previous
//
#include <hip/hip_runtime.h>
#include <hip/hip_bf16.h>

#define NNODES 50000
#define NEDGES 800000
#define NFEAT 128
#define NHID 128
#define NCLASS 10
#define NGRAPHS 256

#define NB 391   // (NNODES+127)/128 buckets of 128 nodes
#define HB 128   // histogram/scatter blocks

typedef __attribute__((ext_vector_type(8))) short short8;
typedef __attribute__((ext_vector_type(4))) short short4v;
typedef __attribute__((ext_vector_type(4))) float floatx4;

__device__ __forceinline__ float bf2f(unsigned short u) {
    union { unsigned i; float f; } c; c.i = ((unsigned)u) << 16; return c.f;
}
__device__ __forceinline__ unsigned short f2bf(float f) {
    union { float f; unsigned i; } c; c.f = f;
    unsigned x = c.i;
    unsigned r = (x + 0x7fffu + ((x >> 16) & 1u)) >> 16;
    return (unsigned short)r;
}
__device__ __forceinline__ float blo(unsigned v) { return bf2f((unsigned short)(v & 0xffffu)); }
__device__ __forceinline__ float bhi(unsigned v) { return bf2f((unsigned short)(v >> 16)); }

__device__ __forceinline__ void gload_lds16(const void* gsrc, void* ldst) {
    __builtin_amdgcn_global_load_lds(
        (const __attribute__((address_space(1))) void*)gsrc,
        (__attribute__((address_space(3))) void*)ldst, 16, 0, 0);
}

// ---------------- atomic-free CSR build: two-level counting sort ----------------
// hist layout TRANSPOSED: hist[bucket * HB + histblock] so bucket rows are contiguous.
__global__ __launch_bounds__(256) void k_hist(const int* __restrict__ dst,
                                              int* __restrict__ hist) {
    __shared__ int lh[NB];
    int tid = threadIdx.x;
    for (int b = tid; b < NB; b += 256) lh[b] = 0;
    __syncthreads();
    for (int i = blockIdx.x * 256 + tid; i < NEDGES; i += HB * 256)
        atomicAdd(&lh[dst[i] >> 7], 1);
    __syncthreads();
    for (int b = tid; b < NB; b += 256) hist[b * HB + blockIdx.x] = lh[b];
}

// Pass 2 (parallel): per-bucket wave scans -> base, bucket totals -> boff.
// Also graph start offsets via binary search on sorted batch.
__global__ __launch_bounds__(512) void k_scan2(const int* __restrict__ hist,
                                               int* __restrict__ base,
                                               int* __restrict__ boff,
                                               int* __restrict__ row_ptr,
                                               const int* __restrict__ batch,
                                               int* __restrict__ gstart) {
    __shared__ int tot[NB];
    int tid = threadIdx.x;
    int wid = tid >> 6, l = tid & 63;
    if (tid <= NGRAPHS) {
        int lo = 0, hi = NNODES;
        while (lo < hi) { int mid = (lo + hi) >> 1; if (batch[mid] < tid) lo = mid + 1; else hi = mid; }
        gstart[tid] = lo;
    }
    for (int q = wid; q < NB; q += 8) {
        int h0 = hist[q * HB + l];
        int h1 = hist[q * HB + 64 + l];
        int s0 = h0, s1 = h1;
        #pragma unroll
        for (int d = 1; d < 64; d <<= 1) {
            int y0 = __shfl_up(s0, d);
            int y1 = __shfl_up(s1, d);
            if (l >= d) { s0 += y0; s1 += y1; }
        }
        int t0 = __shfl(s0, 63);
        base[q * HB + l] = s0 - h0;
        base[q * HB + 64 + l] = s1 - h1 + t0;
        if (l == 63) tot[q] = t0 + s1;
    }
    __syncthreads();
    if (wid == 0) {
        int carry = 0;
        #pragma unroll
        for (int c = 0; c < (NB + 63) / 64; ++c) {
            int i = c * 64 + l;
            int v = (i < NB) ? tot[i] : 0;
            int s = v;
            #pragma unroll
            for (int d = 1; d < 64; d <<= 1) { int y = __shfl_up(s, d); if (l >= d) s += y; }
            if (i < NB) boff[i] = carry + s - v;
            carry += __shfl(s, 63);
        }
        if (l == 0) { boff[NB] = carry; row_ptr[NNODES] = carry; }
    }
}

// Pass 3: scatter edges into bucket-sorted ebuf; LDS cursors = boff + local base.
__global__ __launch_bounds__(256) void k_scatter(const int* __restrict__ src,
                                                 const int* __restrict__ dst,
                                                 const int* __restrict__ base,
                                                 const int* __restrict__ boff,
                                                 unsigned* __restrict__ ebuf) {
    __shared__ int cur[NB];
    int tid = threadIdx.x;
    for (int b = tid; b < NB; b += 256) cur[b] = boff[b] + base[b * HB + blockIdx.x];
    __syncthreads();
    for (int i = blockIdx.x * 256 + tid; i < NEDGES; i += HB * 256) {
        int d = dst[i];
        int bin = d >> 7;
        int pos = atomicAdd(&cur[bin], 1);                    // LDS atomic
        ebuf[pos] = (unsigned)src[i] | ((unsigned)(d & 127) << 16);
    }
}

// Pass 4: per-bucket local CSR (128 nodes) fully in LDS.
__global__ __launch_bounds__(256) void k_bcsr(const unsigned* __restrict__ ebuf,
                                              const int* __restrict__ boff,
                                              int* __restrict__ row_ptr,
                                              int* __restrict__ esrc) {
    __shared__ int deg[128];
    __shared__ int curs[128];
    int tid = threadIdx.x;
    int b = blockIdx.x;
    int s = boff[b], e = boff[b + 1];
    if (tid < 128) deg[tid] = 0;
    __syncthreads();
    for (int i = s + tid; i < e; i += 256) atomicAdd(&deg[ebuf[i] >> 16], 1);
    __syncthreads();
    if (tid == 0) {
        int run = s;
        for (int i = 0; i < 128; ++i) { curs[i] = run; run += deg[i]; }
    }
    __syncthreads();
    if (tid < 128) {
        int node = b * 128 + tid;
        if (node < NNODES) row_ptr[node] = curs[tid];
    }
    __syncthreads();
    for (int i = s + tid; i < e; i += 256) {
        unsigned pk = ebuf[i];
        int pos = atomicAdd(&curs[pk >> 16], 1);              // LDS atomic
        esrc[pos] = (int)(pk & 0xffffu);
    }
}

// ---------------- bf16 conversion (vectorized x4) of x and all 6 W matrices ------
__global__ void k_cvt(const float* __restrict__ x,
                      const float* __restrict__ w0, const float* __restrict__ w1,
                      const float* __restrict__ w2, const float* __restrict__ w3,
                      const float* __restrict__ w4, const float* __restrict__ w5,
                      unsigned short* __restrict__ xb, unsigned short* __restrict__ wb) {
    int gid = blockIdx.x * blockDim.x + threadIdx.x;   // group of 4 elements
    const int NX4 = NNODES * NFEAT / 4;
    const floatx4* srcv;
    short4v* dstv;
    if (gid < NX4) {
        srcv = (const floatx4*)x + gid;
        dstv = (short4v*)xb + gid;
    } else {
        int j = gid - NX4;
        if (j >= 6 * 4096) return;
        int m = j >> 12;
        int o4 = j & 4095;
        const float* w = (m == 0) ? w0 : (m == 1) ? w1 : (m == 2) ? w2
                       : (m == 3) ? w3 : (m == 4) ? w4 : w5;
        srcv = (const floatx4*)w + o4;
        dstv = (short4v*)wb + (m * 4096 + o4);
    }
    floatx4 v = *srcv;
    short4v o;
    #pragma unroll
    for (int k = 0; k < 4; ++k) o[k] = (short)f2bf(v[k]);
    *dstv = o;
}

// ---------------- fused layer: gather-mean into LDS + dual-matvec MFMA -------------
// Per block: 64 output rows. Phase 1: stage 64 feat rows (A2) via global_load_lds,
// 8 waves gather-aggregate 8 nodes each into LDS A1 (XOR-swizzled bf16 rows, f32 acc).
// Phase 2 (after one barrier): v3 MFMA — wave w owns col stripe w*16..w*16+15,
// B fragments in regs, A fragments ds_read from swizzled LDS. +bias, relu, store.
__global__ __launch_bounds__(512, 4) void k_layer(const unsigned short* __restrict__ feat,
                                                  const int* __restrict__ row_ptr,
                                                  const int* __restrict__ esrc,
                                                  const unsigned short* __restrict__ Bn,
                                                  const unsigned short* __restrict__ Bs,
                                                  const float* __restrict__ bias,
                                                  unsigned short* __restrict__ out) {
    __shared__ __align__(16) unsigned short ldsA[2][8192];   // [0]=agg, [1]=feat: 64 rows x 128
    int w = threadIdx.x >> 6;
    int l = threadIdx.x & 63;
    int r = l & 15;               // row-in-tile for A, col-in-tile for B/C
    int gk = l >> 4;              // k-group (8 elements each)
    int m0 = blockIdx.x * 64;

    // ---- stage A2 = feat rows (x @ Ws operand), pre-swizzled source columns ----
    {
        int c = l & 15;
        #pragma unroll
        for (int is = 0; is < 2; ++is) {
            int row = is * 32 + (w << 2) + (l >> 4);
            int nrow = m0 + row; if (nrow >= NNODES) nrow = NNODES - 1;
            gload_lds16(feat + (size_t)nrow * 128 + ((c ^ (row & 15)) << 3),
                        &ldsA[1][(is * 32 + (w << 2)) * 128]);
        }
    }

    // ---- gather-mean 8 nodes per wave into A1 (swizzled write) ----
    const unsigned* feat32 = (const unsigned*)feat;  // 2 bf16/dword, row stride 64
    unsigned* A1 = (unsigned*)&ldsA[0][0];           // dword view, row stride 64
    #pragma unroll 1
    for (int i = 0; i < 8; ++i) {
        int row = (w << 3) + i;
        int n = m0 + row;
        float a0 = 0.f, a1 = 0.f;
        int nb = 0;
        if (n < NNODES) {
            int beg = row_ptr[n];
            nb = row_ptr[n + 1] - beg;
            for (int base = 0; base < nb; base += 64) {
                int rem = nb - base;
                int cnt = rem < 64 ? rem : 64;
                int myidx = (l < cnt) ? esrc[beg + base + l] : 0;
                int j = 0;
                for (; j + 4 <= cnt; j += 4) {
                    int s0 = __shfl(myidx, j);
                    int s1 = __shfl(myidx, j + 1);
                    int s2 = __shfl(myidx, j + 2);
                    int s3 = __shfl(myidx, j + 3);
                    unsigned v0 = feat32[s0 * 64 + l];
                    unsigned v1 = feat32[s1 * 64 + l];
                    unsigned v2 = feat32[s2 * 64 + l];
                    unsigned v3 = feat32[s3 * 64 + l];
                    a0 += (blo(v0) + blo(v1)) + (blo(v2) + blo(v3));
                    a1 += (bhi(v0) + bhi(v1)) + (bhi(v2) + bhi(v3));
                }
                for (; j < cnt; ++j) {
                    int s0 = __shfl(myidx, j);
                    unsigned v0 = feat32[s0 * 64 + l];
                    a0 += blo(v0);
                    a1 += bhi(v0);
                }
            }
        }
        float inv = 1.0f / (float)max(nb, 1);
        unsigned o = ((unsigned)f2bf(a0 * inv)) | (((unsigned)f2bf(a1 * inv)) << 16);
        int c = l >> 2;                                  // logical 16B chunk 0..15
        A1[row * 64 + ((c ^ (row & 15)) << 2) + (l & 3)] = o;   // swizzled write
    }

    // ---- B fragments (L2-hot, 8 loads) issued before the barrier wait ----
    short8 bf[8];
    #pragma unroll
    for (int kt = 0; kt < 8; ++kt) {
        const unsigned short* Bbase = (kt < 4 ? Bn : Bs);
        bf[kt] = *(const short8*)(Bbase + (w * 16 + r) * 128 + (kt & 3) * 32 + gk * 8);
    }
    int o = w * 16 + r;
    float bias_v = bias[o];

    __syncthreads();   // drains vmcnt (gload_lds) + lgkm (ds_write) for all waves

    // ---- MFMA phase: 4 row-tiles of 16 ----
    #pragma unroll
    for (int t = 0; t < 4; ++t) {
        short8 af[8];
        #pragma unroll
        for (int kt = 0; kt < 8; ++kt) {
            int half = kt >> 2;                          // 0: agg@Wn, 1: feat@Ws
            int Cr = ((((kt & 3) << 2) + gk) ^ r) << 3;  // swizzled read col
            af[kt] = *(const short8*)(&ldsA[half][(t * 16 + r) * 128 + Cr]);
        }
        floatx4 acc = {0.f, 0.f, 0.f, 0.f};
        #pragma unroll
        for (int kt = 0; kt < 8; ++kt)
            acc = __builtin_amdgcn_mfma_f32_16x16x32_bf16(af[kt], bf[kt], acc, 0, 0, 0);
        // C/D layout: col = lane&15 (=r), row-in-tile = gk*4 + j
        #pragma unroll
        for (int j = 0; j < 4; ++j) {
            int mrow = m0 + t * 16 + gk * 4 + j;
            if (mrow < NNODES) {
                float v = acc[j] + bias_v;
                v = v > 0.f ? v : 0.f;
                out[mrow * 128 + o] = f2bf(v);
            }
        }
    }
}

// ---------------- mean pool: 8 partial-sum blocks per graph ----------------
__global__ __launch_bounds__(256) void k_pool(const unsigned short* __restrict__ h,
                                              const int* __restrict__ gstart,
                                              float* __restrict__ part) {
    int g = blockIdx.x >> 3;
    int c = blockIdx.x & 7;
    int s = gstart[g], e = gstart[g + 1];
    int len = e - s;
    int cs = s + (len * c) / 8;
    int ce = s + (len * (c + 1)) / 8;
    int w = threadIdx.x >> 6;
    int l = threadIdx.x & 63;
    const unsigned* h32 = (const unsigned*)h;
    float a0 = 0.f, a1 = 0.f;
    for (int n = cs + w; n < ce; n += 4) {
        unsigned v = h32[n * 64 + l];
        a0 += blo(v);
        a1 += bhi(v);
    }
    __shared__ float red[4][128];
    red[w][2 * l] = a0;
    red[w][2 * l + 1] = a1;
    __syncthreads();
    if (w == 0) {
        float r0 = (red[0][2 * l] + red[1][2 * l]) + (red[2][2 * l] + red[3][2 * l]);
        float r1 = (red[0][2 * l + 1] + red[1][2 * l + 1]) + (red[2][2 * l + 1] + red[3][2 * l + 1]);
        float* dst = part + (size_t)(g * 8 + c) * 128;
        dst[2 * l] = r0;
        dst[2 * l + 1] = r1;
    }
}

// ---------------- head: reduce partials, logits + log_softmax (f32) ----------------
__global__ __launch_bounds__(128) void k_head(const float* __restrict__ part,
                                              const int* __restrict__ gstart,
                                              const float* __restrict__ Wlin,
                                              const float* __restrict__ blin,
                                              float* __restrict__ out) {
    int gi = blockIdx.x;
    __shared__ float gl[128];
    __shared__ float lg[NCLASS];
    int t = threadIdx.x;
    float s = 0.f;
    #pragma unroll
    for (int c = 0; c < 8; ++c) s += part[(size_t)(gi * 8 + c) * 128 + t];
    int len = gstart[gi + 1] - gstart[gi];
    gl[t] = s / (float)max(len, 1);
    __syncthreads();
    if (t < NCLASS) {
        float a = blin[t];
        #pragma unroll 16
        for (int i = 0; i < 128; ++i) a += gl[i] * Wlin[t * 128 + i];
        lg[t] = a;
    }
    __syncthreads();
    if (t == 0) {
        float m = lg[0];
        for (int k = 1; k < NCLASS; ++k) m = fmaxf(m, lg[k]);
        float sum = 0.f;
        for (int k = 0; k < NCLASS; ++k) sum += expf(lg[k] - m);
        float ls = logf(sum) + m;
        for (int k = 0; k < NCLASS; ++k) out[gi * NCLASS + k] = lg[k] - ls;
    }
}

extern "C" void kernel_launch(void* const* d_in, const int* in_sizes, int n_in,
                              void* d_out, int out_size, void* d_ws, size_t ws_size,
                              hipStream_t stream) {
    const float* x    = (const float*)d_in[0];
    const int*   ei   = (const int*)d_in[1];
    const int*   src  = ei;
    const int*   dst  = ei + NEDGES;
    const int*   batch= (const int*)d_in[2];
    const float* W1n  = (const float*)d_in[3];
    const float* b1   = (const float*)d_in[4];
    const float* W1s  = (const float*)d_in[5];
    const float* W2n  = (const float*)d_in[6];
    const float* b2   = (const float*)d_in[7];
    const float* W2s  = (const float*)d_in[8];
    const float* W3n  = (const float*)d_in[9];
    const float* b3   = (const float*)d_in[10];
    const float* W3s  = (const float*)d_in[11];
    const float* Wlin = (const float*)d_in[12];
    const float* blin = (const float*)d_in[13];
    float* out = (float*)d_out;

    char* p = (char*)d_ws;
    auto alloc = [&](size_t bytes) -> void* {
        void* r = (void*)p;
        p += (bytes + 255) & ~(size_t)255;
        return r;
    };
    unsigned short* xb   = (unsigned short*)alloc((size_t)NNODES * NFEAT * 2);
    unsigned short* hA   = (unsigned short*)alloc((size_t)NNODES * NHID * 2);
    unsigned short* hB   = (unsigned short*)alloc((size_t)NNODES * NHID * 2);
    unsigned short* wb   = (unsigned short*)alloc((size_t)6 * 16384 * 2);
    int* hist    = (int*)alloc((size_t)NB * HB * 4);
    int* base    = (int*)alloc((size_t)NB * HB * 4);
    int* boff    = (int*)alloc((size_t)(NB + 1) * 4);
    int* row_ptr = (int*)alloc((size_t)(NNODES + 1) * 4);
    int* gstart  = (int*)alloc((size_t)(NGRAPHS + 1) * 4);
    unsigned* ebuf = (unsigned*)alloc((size_t)NEDGES * 4);
    int* esrc    = (int*)alloc((size_t)NEDGES * 4);
    float* part  = (float*)alloc((size_t)NGRAPHS * 8 * NHID * 4);

    // CSR build (atomic-free counting sort) + graph ranges
    k_hist<<<HB, 256, 0, stream>>>(dst, hist);
    k_scan2<<<1, 512, 0, stream>>>(hist, base, boff, row_ptr, batch, gstart);
    k_scatter<<<HB, 256, 0, stream>>>(src, dst, base, boff, ebuf);
    k_bcsr<<<NB, 256, 0, stream>>>(ebuf, boff, row_ptr, esrc);

    // convert x + weights to bf16 (4 elems/thread)
    {
        int total4 = NNODES * NFEAT / 4 + 6 * 4096;
        k_cvt<<<(total4 + 255) / 256, 256, 0, stream>>>(x, W1n, W1s, W2n, W2s, W3n, W3s, xb, wb);
    }

    const int layerGrid = (NNODES + 63) / 64;

    // fused layers: gather-mean + [agg|feat] @ [Wn|Ws]^T + bias + relu
    k_layer<<<layerGrid, 512, 0, stream>>>(xb, row_ptr, esrc, wb + 0 * 16384, wb + 1 * 16384, b1, hA);
    k_layer<<<layerGrid, 512, 0, stream>>>(hA, row_ptr, esrc, wb + 2 * 16384, wb + 3 * 16384, b2, hB);
    k_layer<<<layerGrid, 512, 0, stream>>>(hB, row_ptr, esrc, wb + 4 * 16384, wb + 5 * 16384, b3, hA);

    // pool + head
    k_pool<<<NGRAPHS * 8, 256, 0, stream>>>(hA, gstart, part);
    k_head<<<NGRAPHS, 128, 0, stream>>>(part, gstart, Wlin, blin, out);
}

// Round 8
// 204.972 us; speedup vs baseline: 1.3370x; 1.0219x over previous
//
#include <hip/hip_runtime.h>
#include <hip/hip_bf16.h>

#define NNODES 50000
#define NEDGES 800000
#define NFEAT 128
#define NHID 128
#define NCLASS 10
#define NGRAPHS 256

#define NB 391   // (NNODES+127)/128 buckets of 128 nodes
#define HB 128   // histogram/scatter blocks

typedef __attribute__((ext_vector_type(8))) short short8;
typedef __attribute__((ext_vector_type(4))) short short4v;
typedef __attribute__((ext_vector_type(4))) float floatx4;

__device__ __forceinline__ float bf2f(unsigned short u) {
    union { unsigned i; float f; } c; c.i = ((unsigned)u) << 16; return c.f;
}
__device__ __forceinline__ unsigned short f2bf(float f) {
    union { float f; unsigned i; } c; c.f = f;
    unsigned x = c.i;
    unsigned r = (x + 0x7fffu + ((x >> 16) & 1u)) >> 16;
    return (unsigned short)r;
}
__device__ __forceinline__ float blo(unsigned v) { return bf2f((unsigned short)(v & 0xffffu)); }
__device__ __forceinline__ float bhi(unsigned v) { return bf2f((unsigned short)(v >> 16)); }

__device__ __forceinline__ void gload_lds16(const void* gsrc, void* ldst) {
    __builtin_amdgcn_global_load_lds(
        (const __attribute__((address_space(1))) void*)gsrc,
        (__attribute__((address_space(3))) void*)ldst, 16, 0, 0);
}

// ---------------- atomic-free CSR build: two-level counting sort ----------------
// hist layout TRANSPOSED: hist[bucket * HB + histblock] so bucket rows are contiguous.
__global__ __launch_bounds__(256) void k_hist(const int* __restrict__ dst,
                                              int* __restrict__ hist) {
    __shared__ int lh[NB];
    int tid = threadIdx.x;
    for (int b = tid; b < NB; b += 256) lh[b] = 0;
    __syncthreads();
    for (int i = blockIdx.x * 256 + tid; i < NEDGES; i += HB * 256)
        atomicAdd(&lh[dst[i] >> 7], 1);
    __syncthreads();
    for (int b = tid; b < NB; b += 256) hist[b * HB + blockIdx.x] = lh[b];
}

// Pass 2 (parallel): per-bucket wave scans -> base, bucket totals -> boff.
// Also graph start offsets via binary search on sorted batch.
__global__ __launch_bounds__(512) void k_scan2(const int* __restrict__ hist,
                                               int* __restrict__ base,
                                               int* __restrict__ boff,
                                               int* __restrict__ row_ptr,
                                               const int* __restrict__ batch,
                                               int* __restrict__ gstart) {
    __shared__ int tot[NB];
    int tid = threadIdx.x;
    int wid = tid >> 6, l = tid & 63;
    if (tid <= NGRAPHS) {
        int lo = 0, hi = NNODES;
        while (lo < hi) { int mid = (lo + hi) >> 1; if (batch[mid] < tid) lo = mid + 1; else hi = mid; }
        gstart[tid] = lo;
    }
    for (int q = wid; q < NB; q += 8) {
        int h0 = hist[q * HB + l];
        int h1 = hist[q * HB + 64 + l];
        int s0 = h0, s1 = h1;
        #pragma unroll
        for (int d = 1; d < 64; d <<= 1) {
            int y0 = __shfl_up(s0, d);
            int y1 = __shfl_up(s1, d);
            if (l >= d) { s0 += y0; s1 += y1; }
        }
        int t0 = __shfl(s0, 63);
        base[q * HB + l] = s0 - h0;
        base[q * HB + 64 + l] = s1 - h1 + t0;
        if (l == 63) tot[q] = t0 + s1;
    }
    __syncthreads();
    if (wid == 0) {
        int carry = 0;
        #pragma unroll
        for (int c = 0; c < (NB + 63) / 64; ++c) {
            int i = c * 64 + l;
            int v = (i < NB) ? tot[i] : 0;
            int s = v;
            #pragma unroll
            for (int d = 1; d < 64; d <<= 1) { int y = __shfl_up(s, d); if (l >= d) s += y; }
            if (i < NB) boff[i] = carry + s - v;
            carry += __shfl(s, 63);
        }
        if (l == 0) { boff[NB] = carry; row_ptr[NNODES] = carry; }
    }
}

// Pass 3: scatter edges into bucket-sorted ebuf; LDS cursors = boff + local base.
__global__ __launch_bounds__(256) void k_scatter(const int* __restrict__ src,
                                                 const int* __restrict__ dst,
                                                 const int* __restrict__ base,
                                                 const int* __restrict__ boff,
                                                 unsigned* __restrict__ ebuf) {
    __shared__ int cur[NB];
    int tid = threadIdx.x;
    for (int b = tid; b < NB; b += 256) cur[b] = boff[b] + base[b * HB + blockIdx.x];
    __syncthreads();
    for (int i = blockIdx.x * 256 + tid; i < NEDGES; i += HB * 256) {
        int d = dst[i];
        int bin = d >> 7;
        int pos = atomicAdd(&cur[bin], 1);                    // LDS atomic
        ebuf[pos] = (unsigned)src[i] | ((unsigned)(d & 127) << 16);
    }
}

// Pass 4: per-bucket local CSR (128 nodes) fully in LDS.
__global__ __launch_bounds__(256) void k_bcsr(const unsigned* __restrict__ ebuf,
                                              const int* __restrict__ boff,
                                              int* __restrict__ row_ptr,
                                              int* __restrict__ esrc) {
    __shared__ int deg[128];
    __shared__ int curs[128];
    int tid = threadIdx.x;
    int b = blockIdx.x;
    int s = boff[b], e = boff[b + 1];
    if (tid < 128) deg[tid] = 0;
    __syncthreads();
    for (int i = s + tid; i < e; i += 256) atomicAdd(&deg[ebuf[i] >> 16], 1);
    __syncthreads();
    if (tid == 0) {
        int run = s;
        for (int i = 0; i < 128; ++i) { curs[i] = run; run += deg[i]; }
    }
    __syncthreads();
    if (tid < 128) {
        int node = b * 128 + tid;
        if (node < NNODES) row_ptr[node] = curs[tid];
    }
    __syncthreads();
    for (int i = s + tid; i < e; i += 256) {
        unsigned pk = ebuf[i];
        int pos = atomicAdd(&curs[pk >> 16], 1);              // LDS atomic
        esrc[pos] = (int)(pk & 0xffffu);
    }
}

// ---------------- bf16 conversion (vectorized x4) of x and all 6 W matrices ------
__global__ void k_cvt(const float* __restrict__ x,
                      const float* __restrict__ w0, const float* __restrict__ w1,
                      const float* __restrict__ w2, const float* __restrict__ w3,
                      const float* __restrict__ w4, const float* __restrict__ w5,
                      unsigned short* __restrict__ xb, unsigned short* __restrict__ wb) {
    int gid = blockIdx.x * blockDim.x + threadIdx.x;   // group of 4 elements
    const int NX4 = NNODES * NFEAT / 4;
    const floatx4* srcv;
    short4v* dstv;
    if (gid < NX4) {
        srcv = (const floatx4*)x + gid;
        dstv = (short4v*)xb + gid;
    } else {
        int j = gid - NX4;
        if (j >= 6 * 4096) return;
        int m = j >> 12;
        int o4 = j & 4095;
        const float* w = (m == 0) ? w0 : (m == 1) ? w1 : (m == 2) ? w2
                       : (m == 3) ? w3 : (m == 4) ? w4 : w5;
        srcv = (const floatx4*)w + o4;
        dstv = (short4v*)wb + (m * 4096 + o4);
    }
    floatx4 v = *srcv;
    short4v o;
    #pragma unroll
    for (int k = 0; k < 4; ++k) o[k] = (short)f2bf(v[k]);
    *dstv = o;
}

// ---------------- fused layer: gather-mean into LDS + dual-matvec MFMA -------------
// Per block: 64 output rows. Phase 1: stage 64 feat rows (A2) via global_load_lds,
// 8 waves gather-aggregate 8 nodes each into LDS A1 (XOR-swizzled bf16 rows, f32 acc),
// 8 row-loads in flight per wave. Phase 2 (one barrier): wave w owns col stripe w,
// B fragments in regs, A fragments ds_read from swizzled LDS in 2 K-halves. bias+relu.
__global__ __launch_bounds__(512, 6) void k_layer(const unsigned short* __restrict__ feat,
                                                  const int* __restrict__ row_ptr,
                                                  const int* __restrict__ esrc,
                                                  const unsigned short* __restrict__ Bn,
                                                  const unsigned short* __restrict__ Bs,
                                                  const float* __restrict__ bias,
                                                  unsigned short* __restrict__ out) {
    __shared__ __align__(16) unsigned short ldsA[2][8192];   // [0]=agg, [1]=feat: 64 rows x 128
    int w = threadIdx.x >> 6;
    int l = threadIdx.x & 63;
    int r = l & 15;               // row-in-tile for A, col-in-tile for B/C
    int gk = l >> 4;              // k-group (8 elements each)
    int m0 = blockIdx.x * 64;

    // ---- stage A2 = feat rows (x @ Ws operand), pre-swizzled source columns ----
    {
        int c = l & 15;
        #pragma unroll
        for (int is = 0; is < 2; ++is) {
            int row = is * 32 + (w << 2) + (l >> 4);
            int nrow = m0 + row; if (nrow >= NNODES) nrow = NNODES - 1;
            gload_lds16(feat + (size_t)nrow * 128 + ((c ^ (row & 15)) << 3),
                        &ldsA[1][(is * 32 + (w << 2)) * 128]);
        }
    }

    // ---- gather-mean 8 nodes per wave into A1 (swizzled write), 8-deep MLP ----
    const unsigned* feat32 = (const unsigned*)feat;  // 2 bf16/dword, row stride 64
    unsigned* A1 = (unsigned*)&ldsA[0][0];           // dword view, row stride 64
    #pragma unroll 1
    for (int i = 0; i < 8; ++i) {
        int row = (w << 3) + i;
        int n = m0 + row;
        float a0 = 0.f, a1 = 0.f;
        int nb = 0;
        if (n < NNODES) {
            int beg = row_ptr[n];
            nb = row_ptr[n + 1] - beg;
            for (int base = 0; base < nb; base += 64) {
                int rem = nb - base;
                int cnt = rem < 64 ? rem : 64;
                int myidx = (l < cnt) ? esrc[beg + base + l] : 0;
                int j = 0;
                for (; j + 8 <= cnt; j += 8) {
                    int s0 = __shfl(myidx, j);
                    int s1 = __shfl(myidx, j + 1);
                    int s2 = __shfl(myidx, j + 2);
                    int s3 = __shfl(myidx, j + 3);
                    int s4 = __shfl(myidx, j + 4);
                    int s5 = __shfl(myidx, j + 5);
                    int s6 = __shfl(myidx, j + 6);
                    int s7 = __shfl(myidx, j + 7);
                    unsigned v0 = feat32[s0 * 64 + l];
                    unsigned v1 = feat32[s1 * 64 + l];
                    unsigned v2 = feat32[s2 * 64 + l];
                    unsigned v3 = feat32[s3 * 64 + l];
                    unsigned v4 = feat32[s4 * 64 + l];
                    unsigned v5 = feat32[s5 * 64 + l];
                    unsigned v6 = feat32[s6 * 64 + l];
                    unsigned v7 = feat32[s7 * 64 + l];
                    a0 += ((blo(v0) + blo(v1)) + (blo(v2) + blo(v3)))
                        + ((blo(v4) + blo(v5)) + (blo(v6) + blo(v7)));
                    a1 += ((bhi(v0) + bhi(v1)) + (bhi(v2) + bhi(v3)))
                        + ((bhi(v4) + bhi(v5)) + (bhi(v6) + bhi(v7)));
                }
                for (; j + 4 <= cnt; j += 4) {
                    int s0 = __shfl(myidx, j);
                    int s1 = __shfl(myidx, j + 1);
                    int s2 = __shfl(myidx, j + 2);
                    int s3 = __shfl(myidx, j + 3);
                    unsigned v0 = feat32[s0 * 64 + l];
                    unsigned v1 = feat32[s1 * 64 + l];
                    unsigned v2 = feat32[s2 * 64 + l];
                    unsigned v3 = feat32[s3 * 64 + l];
                    a0 += (blo(v0) + blo(v1)) + (blo(v2) + blo(v3));
                    a1 += (bhi(v0) + bhi(v1)) + (bhi(v2) + bhi(v3));
                }
                for (; j < cnt; ++j) {
                    int s0 = __shfl(myidx, j);
                    unsigned v0 = feat32[s0 * 64 + l];
                    a0 += blo(v0);
                    a1 += bhi(v0);
                }
            }
        }
        float inv = 1.0f / (float)max(nb, 1);
        unsigned o = ((unsigned)f2bf(a0 * inv)) | (((unsigned)f2bf(a1 * inv)) << 16);
        int c = l >> 2;                                  // logical 16B chunk 0..15
        A1[row * 64 + ((c ^ (row & 15)) << 2) + (l & 3)] = o;   // swizzled write
    }

    // ---- B fragments (L2-hot, 8 loads) issued before the barrier wait ----
    short8 bf[8];
    #pragma unroll
    for (int kt = 0; kt < 8; ++kt) {
        const unsigned short* Bbase = (kt < 4 ? Bn : Bs);
        bf[kt] = *(const short8*)(Bbase + (w * 16 + r) * 128 + (kt & 3) * 32 + gk * 8);
    }
    int o = w * 16 + r;
    float bias_v = bias[o];

    __syncthreads();   // drains vmcnt (gload_lds) + lgkm (ds_write) for all waves

    // ---- MFMA phase: 4 row-tiles of 16; K processed in 2 halves (VGPR economy) ----
    #pragma unroll
    for (int t = 0; t < 4; ++t) {
        floatx4 acc = {0.f, 0.f, 0.f, 0.f};
        #pragma unroll
        for (int half = 0; half < 2; ++half) {           // 0: agg@Wn, 1: feat@Ws
            short8 af[4];
            #pragma unroll
            for (int kk = 0; kk < 4; ++kk) {
                int Cr = (((kk << 2) + gk) ^ r) << 3;    // swizzled read col
                af[kk] = *(const short8*)(&ldsA[half][(t * 16 + r) * 128 + Cr]);
            }
            #pragma unroll
            for (int kk = 0; kk < 4; ++kk)
                acc = __builtin_amdgcn_mfma_f32_16x16x32_bf16(af[kk], bf[half * 4 + kk], acc, 0, 0, 0);
        }
        // C/D layout: col = lane&15 (=r), row-in-tile = gk*4 + j
        #pragma unroll
        for (int j = 0; j < 4; ++j) {
            int mrow = m0 + t * 16 + gk * 4 + j;
            if (mrow < NNODES) {
                float v = acc[j] + bias_v;
                v = v > 0.f ? v : 0.f;
                out[mrow * 128 + o] = f2bf(v);
            }
        }
    }
}

// ---------------- mean pool: 8 partial-sum blocks per graph ----------------
__global__ __launch_bounds__(256) void k_pool(const unsigned short* __restrict__ h,
                                              const int* __restrict__ gstart,
                                              float* __restrict__ part) {
    int g = blockIdx.x >> 3;
    int c = blockIdx.x & 7;
    int s = gstart[g], e = gstart[g + 1];
    int len = e - s;
    int cs = s + (len * c) / 8;
    int ce = s + (len * (c + 1)) / 8;
    int w = threadIdx.x >> 6;
    int l = threadIdx.x & 63;
    const unsigned* h32 = (const unsigned*)h;
    float a0 = 0.f, a1 = 0.f;
    for (int n = cs + w; n < ce; n += 4) {
        unsigned v = h32[n * 64 + l];
        a0 += blo(v);
        a1 += bhi(v);
    }
    __shared__ float red[4][128];
    red[w][2 * l] = a0;
    red[w][2 * l + 1] = a1;
    __syncthreads();
    if (w == 0) {
        float r0 = (red[0][2 * l] + red[1][2 * l]) + (red[2][2 * l] + red[3][2 * l]);
        float r1 = (red[0][2 * l + 1] + red[1][2 * l + 1]) + (red[2][2 * l + 1] + red[3][2 * l + 1]);
        float* dst = part + (size_t)(g * 8 + c) * 128;
        dst[2 * l] = r0;
        dst[2 * l + 1] = r1;
    }
}

// ---------------- head: reduce partials, logits + log_softmax (f32) ----------------
__global__ __launch_bounds__(128) void k_head(const float* __restrict__ part,
                                              const int* __restrict__ gstart,
                                              const float* __restrict__ Wlin,
                                              const float* __restrict__ blin,
                                              float* __restrict__ out) {
    int gi = blockIdx.x;
    __shared__ float gl[128];
    __shared__ float lg[NCLASS];
    int t = threadIdx.x;
    float s = 0.f;
    #pragma unroll
    for (int c = 0; c < 8; ++c) s += part[(size_t)(gi * 8 + c) * 128 + t];
    int len = gstart[gi + 1] - gstart[gi];
    gl[t] = s / (float)max(len, 1);
    __syncthreads();
    if (t < NCLASS) {
        float a = blin[t];
        #pragma unroll 16
        for (int i = 0; i < 128; ++i) a += gl[i] * Wlin[t * 128 + i];
        lg[t] = a;
    }
    __syncthreads();
    if (t == 0) {
        float m = lg[0];
        for (int k = 1; k < NCLASS; ++k) m = fmaxf(m, lg[k]);
        float sum = 0.f;
        for (int k = 0; k < NCLASS; ++k) sum += expf(lg[k] - m);
        float ls = logf(sum) + m;
        for (int k = 0; k < NCLASS; ++k) out[gi * NCLASS + k] = lg[k] - ls;
    }
}

extern "C" void kernel_launch(void* const* d_in, const int* in_sizes, int n_in,
                              void* d_out, int out_size, void* d_ws, size_t ws_size,
                              hipStream_t stream) {
    const float* x    = (const float*)d_in[0];
    const int*   ei   = (const int*)d_in[1];
    const int*   src  = ei;
    const int*   dst  = ei + NEDGES;
    const int*   batch= (const int*)d_in[2];
    const float* W1n  = (const float*)d_in[3];
    const float* b1   = (const float*)d_in[4];
    const float* W1s  = (const float*)d_in[5];
    const float* W2n  = (const float*)d_in[6];
    const float* b2   = (const float*)d_in[7];
    const float* W2s  = (const float*)d_in[8];
    const float* W3n  = (const float*)d_in[9];
    const float* b3   = (const float*)d_in[10];
    const float* W3s  = (const float*)d_in[11];
    const float* Wlin = (const float*)d_in[12];
    const float* blin = (const float*)d_in[13];
    float* out = (float*)d_out;

    char* p = (char*)d_ws;
    auto alloc = [&](size_t bytes) -> void* {
        void* r = (void*)p;
        p += (bytes + 255) & ~(size_t)255;
        return r;
    };
    unsigned short* xb   = (unsigned short*)alloc((size_t)NNODES * NFEAT * 2);
    unsigned short* hA   = (unsigned short*)alloc((size_t)NNODES * NHID * 2);
    unsigned short* hB   = (unsigned short*)alloc((size_t)NNODES * NHID * 2);
    unsigned short* wb   = (unsigned short*)alloc((size_t)6 * 16384 * 2);
    int* hist    = (int*)alloc((size_t)NB * HB * 4);
    int* base    = (int*)alloc((size_t)NB * HB * 4);
    int* boff    = (int*)alloc((size_t)(NB + 1) * 4);
    int* row_ptr = (int*)alloc((size_t)(NNODES + 1) * 4);
    int* gstart  = (int*)alloc((size_t)(NGRAPHS + 1) * 4);
    unsigned* ebuf = (unsigned*)alloc((size_t)NEDGES * 4);
    int* esrc    = (int*)alloc((size_t)NEDGES * 4);
    float* part  = (float*)alloc((size_t)NGRAPHS * 8 * NHID * 4);

    // CSR build (atomic-free counting sort) + graph ranges
    k_hist<<<HB, 256, 0, stream>>>(dst, hist);
    k_scan2<<<1, 512, 0, stream>>>(hist, base, boff, row_ptr, batch, gstart);
    k_scatter<<<HB, 256, 0, stream>>>(src, dst, base, boff, ebuf);
    k_bcsr<<<NB, 256, 0, stream>>>(ebuf, boff, row_ptr, esrc);

    // convert x + weights to bf16 (4 elems/thread)
    {
        int total4 = NNODES * NFEAT / 4 + 6 * 4096;
        k_cvt<<<(total4 + 255) / 256, 256, 0, stream>>>(x, W1n, W1s, W2n, W2s, W3n, W3s, xb, wb);
    }

    const int layerGrid = (NNODES + 63) / 64;

    // fused layers: gather-mean + [agg|feat] @ [Wn|Ws]^T + bias + relu
    k_layer<<<layerGrid, 512, 0, stream>>>(xb, row_ptr, esrc, wb + 0 * 16384, wb + 1 * 16384, b1, hA);
    k_layer<<<layerGrid, 512, 0, stream>>>(hA, row_ptr, esrc, wb + 2 * 16384, wb + 3 * 16384, b2, hB);
    k_layer<<<layerGrid, 512, 0, stream>>>(hB, row_ptr, esrc, wb + 4 * 16384, wb + 5 * 16384, b3, hA);

    // pool + head
    k_pool<<<NGRAPHS * 8, 256, 0, stream>>>(hA, gstart, part);
    k_head<<<NGRAPHS, 128, 0, stream>>>(part, gstart, Wlin, blin, out);
}